// Round 1
// 84.837 us; speedup vs baseline: 1.0115x; 1.0115x over previous
//
#include <hip/hip_runtime.h>
#include <math.h>

#define B_TOTAL 2048
#define I_TOTAL 2048
#define O_TOTAL 2048
#define KW 64
#define NIN 6
#define BLOCK 256
#define TILE_B 16              // b-rows per block
#define CH 2                   // rows per LDS buffer (double-buffered)
#define NCHUNK (TILE_B / CH)   // 8
#define BBLOCKS (B_TOTAL / TILE_B)  /* 128 */
#define OBLOCKS (O_TOTAL / BLOCK)   /* 8   */

// ---------------------------------------------------------------------------
// Prep: wT[k][o] layout (coalesced per-lane weight loads in main).
//   k in [0,32):  wT = sigmoid(table[o][k])                       ("lo")
//   k in [32,64): wT = sigmoid(table[o][k]) - sigmoid(table[o][k-32]) (diff)
// v2: LDS 64x65 transpose so wT writes are coalesced (old version scattered
// 64 cache lines per wave-store). Also mapping -> transposed int32 m32T[i][o].
// Grid: 48 blocks x 256. Blocks 0..31 do the table transpose (64 o's each);
// all blocks cover the 12288 mapping entries.
// ---------------------------------------------------------------------------
__global__ __launch_bounds__(BLOCK) void prep_kernel(
    const float* __restrict__ table,
    const unsigned int* __restrict__ map_raw,
    float* __restrict__ wT,
    int* __restrict__ m32T)
{
    const int t = threadIdx.x;

    if (blockIdx.x < 32) {
        __shared__ float sm[64][65];          // +1 pad: conflict-free col reads
        const int o0 = blockIdx.x * 64;
        #pragma unroll
        for (int rep = 0; rep < 16; ++rep) {
            int idx = rep * 256 + t;          // 0..4095
            int ol = idx >> 6, k = idx & 63;
            float v = table[(o0 + ol) * KW + k];      // coalesced read
            sm[ol][k] = 1.0f / (1.0f + __expf(-v));
        }
        __syncthreads();
        #pragma unroll
        for (int rep = 0; rep < 16; ++rep) {
            int idx = rep * 256 + t;
            int k = idx >> 6, ol = idx & 63;
            float s = sm[ol][k];
            float v = (k >= 32) ? (s - sm[ol][k - 32]) : s;
            wT[k * O_TOTAL + o0 + ol] = v;            // coalesced write
        }
    }

    const int gid = blockIdx.x * BLOCK + t;
    if (gid < O_TOTAL * NIN) {
        // int64 little-endian with values < 2048 => odd u32 words are all 0.
        bool is64 = ((map_raw[1] | map_raw[3] | map_raw[5] | map_raw[7]) == 0u);
        int val = is64 ? (int)map_raw[2 * gid] : (int)map_raw[gid];
        int oo = gid / NIN, ii = gid - oo * NIN;
        m32T[ii * O_TOTAL + oo] = val;
    }
}

// ---------------------------------------------------------------------------
// Main kernel.
// v2 changes vs previous best (84.3us):
//  * async global->LDS staging via global_load_lds width 16 (no VGPR
//    round-trip, no ds_write instructions)
//  * double-buffered CH=2 row chunks: issue DMA for chunk c+1, compute
//    chunk c, then ONE __syncthreads() (its vmcnt(0) drain lands after
//    compute has covered the VMEM latency)  -> staging latency hidden
//  * gathers indexed off xs base with compile-time row constant so the
//    row offset folds into the ds_read 16-bit immediate
//  * __launch_bounds__(256,3): 3 waves/SIMD target; LDS is only 32 KB
// ---------------------------------------------------------------------------
__device__ __forceinline__ void async_cp16(float* lds, const float* g)
{
    __builtin_amdgcn_global_load_lds(
        (const __attribute__((address_space(1))) void*)g,
        (__attribute__((address_space(3))) void*)lds,
        16, 0, 0);
}

__global__ __launch_bounds__(BLOCK, 3) void lut_main(
    const float* __restrict__ x,
    const float* __restrict__ wT,
    const int*   __restrict__ m32T,
    float*       __restrict__ out)
{
    __shared__ float xs[2 * CH * I_TOTAL];   // 2 bufs x 2 rows x 8KB = 32 KB

    const int o    = blockIdx.y * BLOCK + threadIdx.x;
    const int b0   = blockIdx.x * TILE_B;
    const int wave = threadIdx.x >> 6;
    const int lane = threadIdx.x & 63;

    // 64 weights (lo[0:32] + diff[32:64]) -> registers, coalesced loads
    float ww[KW];
    #pragma unroll
    for (int k = 0; k < KW; ++k) ww[k] = wT[k * O_TOTAL + o];

    int m[NIN];
    #pragma unroll
    for (int i = 0; i < NIN; ++i) m[i] = m32T[i * O_TOTAL + o];

    // --- prologue: stage chunk 0 into buf 0 -------------------------------
    // CH rows = 4096 floats; 16 DMA instrs of 1KB; 4 per wave.
    {
        const float* src = x + (size_t)b0 * I_TOTAL;
        #pragma unroll
        for (int ti = 0; ti < 4; ++ti) {
            int off = (wave * 4 + ti) * 256;         // wave-uniform float off
            async_cp16(&xs[off], src + off + lane * 4);
        }
    }
    __syncthreads();   // drains own vmcnt(0), then barrier

    #pragma unroll 2
    for (int c = 0; c < NCHUNK; ++c) {
        const int buf = c & 1;

        // issue DMA for next chunk into the other buffer (latency hidden
        // under this chunk's compute; drained by the trailing syncthreads)
        if (c + 1 < NCHUNK) {
            const float* src = x + (size_t)(b0 + (c + 1) * CH) * I_TOTAL;
            float* dst = &xs[(buf ^ 1) * CH * I_TOTAL];
            #pragma unroll
            for (int ti = 0; ti < 4; ++ti) {
                int off = (wave * 4 + ti) * 256;
                async_cp16(dst + off, src + off + lane * 4);
            }
        }

        #pragma unroll
        for (int cr = 0; cr < CH; ++cr) {
            const int rowc = (buf * CH + cr) * I_TOTAL;   // compile-time
            float xv[NIN];
            #pragma unroll
            for (int i = 0; i < NIN; ++i) xv[i] = xs[rowc + m[i]];  // LDS gather

            // multilinear contraction; level 0 uses precomputed diffs
            float tt[32];
            #pragma unroll
            for (int j = 0; j < 32; ++j) tt[j] = fmaf(xv[5], ww[j + 32], ww[j]);
            #pragma unroll
            for (int j = 0; j < 16; ++j) tt[j] = fmaf(xv[4], tt[j + 16] - tt[j], tt[j]);
            #pragma unroll
            for (int j = 0; j < 8;  ++j) tt[j] = fmaf(xv[3], tt[j + 8]  - tt[j], tt[j]);
            #pragma unroll
            for (int j = 0; j < 4;  ++j) tt[j] = fmaf(xv[2], tt[j + 4]  - tt[j], tt[j]);
            #pragma unroll
            for (int j = 0; j < 2;  ++j) tt[j] = fmaf(xv[1], tt[j + 2]  - tt[j], tt[j]);
            float res = fmaf(xv[0], tt[1] - tt[0], tt[0]);

            out[(size_t)(b0 + c * CH + cr) * O_TOTAL + o] = res;  // coalesced
        }

        __syncthreads();  // own DMA drained (vmcnt 0) + all waves done with buf
    }
}

extern "C" void kernel_launch(void* const* d_in, const int* in_sizes, int n_in,
                              void* d_out, int out_size, void* d_ws, size_t ws_size,
                              hipStream_t stream)
{
    const float*        x       = (const float*)d_in[0];
    const float*        table   = (const float*)d_in[1];
    const unsigned int* map_raw = (const unsigned int*)d_in[2];
    float* out  = (float*)d_out;
    float* wT   = (float*)d_ws;                                        // 512 KB
    int*   m32T = (int*)((char*)d_ws + (size_t)O_TOTAL * KW * sizeof(float)); // +48 KB

    prep_kernel<<<48, BLOCK, 0, stream>>>(table, map_raw, wT, m32T);

    dim3 grid(BBLOCKS, OBLOCKS);
    lut_main<<<grid, dim3(BLOCK), 0, stream>>>(x, wT, m32T, out);
}